// Round 6
// baseline (1831.594 us; speedup 1.0000x reference)
//
#include <hip/hip_runtime.h>
#include <hip/hip_fp16.h>
#include <math.h>

#define TAU 0.5f   // |pivot|^2 threshold (f32) for the fast pivot path

// ---------------------------------------------------------------------------
// Fused kernel: 2304 blocks x 256 threads (9 blocks/CU EXACTLY -- r21 delta).
//   bid < 256   -> conv block,  cid = bid
//   bid >= 256  -> logdet block, lid = bid-256 (0..2047); blocks lid<2 run
//                  TWO keys (lid and lid+2048) back-to-back. They are
//                  dispatched first, so the double work finishes early --
//                  removes the 2-CU 10th-block tail of the 2306 grid.
//
// r21 main delta: LDS pivot-row broadcast replaces the readlane broadcast.
//   r0-r5 invariant: VALUBusy*dur ~= 180us aggregate = logdet VALU work;
//   dur only ever approached it. Readlanes were ~2100/wave (1/col/k, the
//   largest removable VALU class; pk_fma 2/col is the arithmetic floor).
//   New: lane p dumps row slots 1..64 as <=16 exec-masked ds_write_b128
//   (float4 built BY VALUE -- no &a2[], keeps a2 in registers), all lanes
//   re-read via 2 ds_read_b128 per 8-col chunk (same-addr broadcast,
//   conflict-free). Per k: ~32 VALU readlane -> ~16 DS ops on an idle pipe.
//   (r8's regression was per-value ds_bpermute -- 4x this inst count,
//   unbatched; different design.)
// Conv = r19/r20 verbatim (established -10us). pk_fma inner math unchanged.
// r16-r18 established: LDS column-staging/occupancy arc is a dead end.
// ---------------------------------------------------------------------------
__device__ __forceinline__ int h2i(__half2 h) { int i; __builtin_memcpy(&i, &h, 4); return i; }
__device__ __forceinline__ __half2 i2h(int i) { __half2 h; __builtin_memcpy(&h, &i, 4); return h; }

__global__ __launch_bounds__(256, 3) void fused_kernel(
    const float* __restrict__ x, const float* __restrict__ K,
    const float* __restrict__ bias, float* __restrict__ out,
    float* __restrict__ logdet) {
  __shared__ float smem[4928];               // conv: w[576]+tile[64*68]; logdet: 4x64 ints
  int bid = blockIdx.x;
  int t = threadIdx.x;

  if (bid < 256) {
    // ================= conv =================
    int b = bid >> 6, co = bid & 63;
    float* w = smem;                         // 576
    float* tile = smem + 576;                // 64*68 (stride 68: 16B-aligned)

    for (int i = t; i < 576; i += 256) {
      float vv = K[(size_t)((b * 64 + co) * 64) * 9 + i];
      if (i == co * 9 + 4) vv += 1.0f;       // identity: ci==co, center tap
      w[i] = vv;
    }

    int ty = t >> 2;
    int tx = t & 3;
    int x0 = tx << 4;
    float bval = bias[b * 64 + co];
    float acc[16];
#pragma unroll
    for (int i = 0; i < 16; ++i) acc[i] = bval;

    const float* xb = x + (size_t)(b * 64) * 4096;
    for (int ci = 0; ci < 64; ++ci) {
      __syncthreads();                       // WAR on tile (and w on first iter)
      const float4* xc4 = (const float4*)(xb + (size_t)ci * 4096);
#pragma unroll
      for (int j = 0; j < 4; ++j) {          // 4x (dwordx4 load + b128 LDS write)
        int i4 = t + 256 * j;                // float4 index 0..1023
        int row = i4 >> 4;                   // 16 float4 per 64-wide row
        int col = (i4 & 15) << 2;
        float4 vv = xc4[i4];
        *(float4*)&tile[row * 68 + col] = vv;
      }
      __syncthreads();

      float w0 = w[ci * 9 + 0], w1 = w[ci * 9 + 1], w2 = w[ci * 9 + 2];
      float w3 = w[ci * 9 + 3], w4 = w[ci * 9 + 4], w5 = w[ci * 9 + 5];
      float w6 = w[ci * 9 + 6], w7 = w[ci * 9 + 7], w8 = w[ci * 9 + 8];

      int ym = ((ty - 1) & 63) * 68;
      int yc = ty * 68;
      int yp = ((ty + 1) & 63) * 68;
      float in0[18], in1[18], in2[18];
#pragma unroll
      for (int q = 0; q < 4; ++q) {          // interior: 12x ds_read_b128
        float4 v0 = *(const float4*)&tile[ym + x0 + 4 * q];
        float4 v1 = *(const float4*)&tile[yc + x0 + 4 * q];
        float4 v2 = *(const float4*)&tile[yp + x0 + 4 * q];
        in0[1 + 4 * q] = v0.x; in0[2 + 4 * q] = v0.y; in0[3 + 4 * q] = v0.z; in0[4 + 4 * q] = v0.w;
        in1[1 + 4 * q] = v1.x; in1[2 + 4 * q] = v1.y; in1[3 + 4 * q] = v1.z; in1[4 + 4 * q] = v1.w;
        in2[1 + 4 * q] = v2.x; in2[2 + 4 * q] = v2.y; in2[3 + 4 * q] = v2.z; in2[4 + 4 * q] = v2.w;
      }
      in0[0]  = tile[ym + ((x0 - 1) & 63)];  // 6 scalar edge reads (wrap)
      in0[17] = tile[ym + ((x0 + 16) & 63)];
      in1[0]  = tile[yc + ((x0 - 1) & 63)];
      in1[17] = tile[yc + ((x0 + 16) & 63)];
      in2[0]  = tile[yp + ((x0 - 1) & 63)];
      in2[17] = tile[yp + ((x0 + 16) & 63)];
#pragma unroll
      for (int px = 0; px < 16; ++px) {
        float a = acc[px];
        a = fmaf(w0, in0[px], a); a = fmaf(w1, in0[px + 1], a); a = fmaf(w2, in0[px + 2], a);
        a = fmaf(w3, in1[px], a); a = fmaf(w4, in1[px + 1], a); a = fmaf(w5, in1[px + 2], a);
        a = fmaf(w6, in2[px], a); a = fmaf(w7, in2[px + 1], a); a = fmaf(w8, in2[px + 2], a);
        acc[px] = a;
      }
    }

    float* op = out + (size_t)(b * 64 + co) * 4096 + ty * 64 + x0;
#pragma unroll
    for (int i = 0; i < 16; i += 4) {
      *(float4*)(op + i) = make_float4(acc[i], acc[i + 1], acc[i + 2], acc[i + 3]);
    }
    return;
  }

  // ================= logdet =================
  int lid = bid - 256;                       // 0..2047
  int b = t >> 6;                            // wave id == batch
  int r = t & 63;                            // lane == matrix row
  float4* pivq = (float4*)smem + b * 16;     // per-wave 64-int pivot-row buffer

  int nrep = (lid < 2) ? 2 : 1;
  for (int rep = 0; rep < nrep; ++rep) {
    int key = lid + (rep << 11);             // second key = lid + 2048
    int u, v;
    if (key < 33) { u = 0; v = key; }
    else if (key < 2017) { int q = key - 33; u = 1 + (q >> 6); v = q & 63; }
    else { u = 32; v = key - 2017; }
    float weight = (((u & 31) == 0) && ((v & 31) == 0)) ? 1.0f : 2.0f;

    // twiddles w[kh*3+kw] = e^{-2*pi*i*(u*kh+v*kw)/64} via complex power products
    float Ar[3], Ai[3], Br[3], Bi[3];
    {
      const float k2pi = -6.283185307179586f / 64.0f;
      float su, cu, sv, cv;
      __sincosf(k2pi * (float)u, &su, &cu);
      __sincosf(k2pi * (float)v, &sv, &cv);
      Ar[0] = 1.0f; Ai[0] = 0.0f; Ar[1] = cu; Ai[1] = su;
      Ar[2] = cu * cu - su * su; Ai[2] = 2.0f * cu * su;
      Br[0] = 1.0f; Bi[0] = 0.0f; Br[1] = cv; Bi[1] = sv;
      Br[2] = cv * cv - sv * sv; Bi[2] = 2.0f * cv * sv;
    }
    float wr[9], wi[9];
#pragma unroll
    for (int kh = 0; kh < 3; ++kh)
#pragma unroll
      for (int kw = 0; kw < 3; ++kw) {
        wr[kh * 3 + kw] = Ar[kh] * Br[kw] - Ai[kh] * Bi[kw];
        wi[kh * 3 + kw] = Ar[kh] * Bi[kw] + Ai[kh] * Br[kw];
      }

    // Build row r of Khat in fp32, pack each column to f16x2 immediately.
    __half2 a2[65];
    const float4* Kp4 = (const float4*)(K + (size_t)(b * 64 + r) * 576);
#pragma unroll
    for (int g = 0; g < 16; ++g) {           // 16 groups x 4 columns
      float f[36];
#pragma unroll
      for (int qq = 0; qq < 9; ++qq) {
        float4 vv = Kp4[g * 9 + qq];
        f[qq * 4 + 0] = vv.x; f[qq * 4 + 1] = vv.y; f[qq * 4 + 2] = vv.z; f[qq * 4 + 3] = vv.w;
      }
#pragma unroll
      for (int cc = 0; cc < 4; ++cc) {
        int c = g * 4 + cc;
        float re = 0.0f, im = 0.0f;
#pragma unroll
        for (int t9 = 0; t9 < 9; ++t9) {
          float kv = f[cc * 9 + t9];
          re = fmaf(kv, wr[t9], re);
          im = fmaf(kv, wi[t9], im);
        }
        if (c == r) { re += wr[4]; im += wi[4]; }  // identity: center-tap delta
        a2[c] = __floats2half2_rn(re, im);
      }
    }
    a2[64] = __floats2half2_rn(0.0f, 0.0f);  // pad slot for chunk overshoot

    bool active = true;
    float pivmag = 1.0f;                     // each lane's own pivot |.|^2 (f32)

    for (int k = 0; k < 63; ++k) {
      float fr0 = __low2float(a2[0]);
      float fi0 = __high2float(a2[0]);
      float mag = fmaf(fr0, fr0, fi0 * fi0);
      bool cand = active && (mag >= TAU);
      unsigned long long candm = __ballot(cand);
      int p;
      if (candm != 0ULL) {
        p = __ffsll(candm) - 1;              // fast path: first big-enough pivot
      } else {                               // rare: all remaining pivots tiny
        float mm = active ? mag : -1.0f;
#pragma unroll
        for (int off = 32; off > 0; off >>= 1) mm = fmaxf(mm, __shfl_xor(mm, off));
        unsigned long long mx = __ballot(active && (mag == mm));
        if (mx == 0ULL) mx = __ballot(active); // degenerate (NaN) guard
        p = __ffsll(mx) - 1;
      }
      p &= 63;                               // uniform (ballot-derived), valid lane

      bool isPiv = (r == p);
      pivmag = isPiv ? mag : pivmag;         // latch; log deferred to the end
      active = active && !isPiv;

      int rem = 63 - k;                      // remaining columns at slots 1..rem

      // Pivot-row dump: lane p stores slots 1..rem (pre-update values) as
      // float4s built BY VALUE (a2 stays in registers). Slots beyond rem are
      // stale -- only ever multiplied into dead overshoot slots.
      if (r == p) {
#pragma unroll
        for (int j = 0; j < 16; ++j) {
          if (j * 4 < rem) {
            pivq[j] = make_float4(__int_as_float(h2i(a2[4 * j + 1])),
                                  __int_as_float(h2i(a2[4 * j + 2])),
                                  __int_as_float(h2i(a2[4 * j + 3])),
                                  __int_as_float(h2i(a2[4 * j + 4])));
          }
        }
      }

      __half2 pivh = i2h(__builtin_amdgcn_readlane(h2i(a2[0]), p));
      float pr = __low2float(pivh);
      float pi = __high2float(pivh);
      float inv = __builtin_amdgcn_rcpf(fmaf(pr, pr, pi * pi));
      float fre = (fr0 * pr + fi0 * pi) * inv;
      float fim = (fi0 * pr - fr0 * pi) * inv;
      fre = active ? fre : 0.0f;             // pivot + retired lanes: shift-only
      fim = active ? fim : 0.0f;
      __half2 nfre2 = __float2half2_rn(-fre);                   // (-fre, -fre)
      __half2 fim2 = __halves2half2(__float2half_rn(fim),
                                    __float2half_rn(-fim));     // (fim, -fim)

#pragma unroll
      for (int ch = 0; ch < 8; ++ch) {
        if (ch * 8 < rem) {                  // uniform scalar guard, chunk=8
          int c0 = ch * 8 + 1;
          float4 qa = pivq[2 * ch];          // same-addr broadcast reads
          float4 qb = pivq[2 * ch + 1];
          __half2 P[8];
          P[0] = i2h(__float_as_int(qa.x)); P[1] = i2h(__float_as_int(qa.y));
          P[2] = i2h(__float_as_int(qa.z)); P[3] = i2h(__float_as_int(qa.w));
          P[4] = i2h(__float_as_int(qb.x)); P[5] = i2h(__float_as_int(qb.y));
          P[6] = i2h(__float_as_int(qb.z)); P[7] = i2h(__float_as_int(qb.w));
#pragma unroll
          for (int e = 0; e < 8; ++e) {
            // (re',im') = (re,im) - fre*(lr,li) + fim*(li,-lr): 2 pk_fma
            // (__lowhigh2highlow folds into pk_fma op_sel -- r13 errata)
            __half2 tmp = __hfma2(nfre2, P[e], a2[c0 + e]);
            a2[c0 + e - 1] = __hfma2(fim2, __lowhigh2highlow(P[e]), tmp);
          }
        }
      }
    }
    {
      float fr0 = __low2float(a2[0]);
      float fi0 = __high2float(a2[0]);
      if (active) pivmag = fmaf(fr0, fr0, fi0 * fi0);  // last surviving row
    }

    float logsum = 0.5f * __logf(pivmag);    // one log per lane; sum = logdet
#pragma unroll
    for (int off = 32; off > 0; off >>= 1) logsum += __shfl_xor(logsum, off);
    if (r == 0) atomicAdd(&logdet[b], weight * logsum);
  }
}

// ---------------------------------------------------------------------------
extern "C" void kernel_launch(void* const* d_in, const int* in_sizes, int n_in,
                              void* d_out, int out_size, void* d_ws, size_t ws_size,
                              hipStream_t stream) {
  const float* conv_in = (const float*)d_in[0];   // [4,64,64,64]
  const float* K       = (const float*)d_in[1];   // [4,64,64,3,3]
  const float* bias    = (const float*)d_in[2];   // [4,64,1,1]
  float* out = (float*)d_out;                     // conv_out (1048576) ++ logdet (4)
  float* logdet = out + 1048576;

  hipMemsetAsync(logdet, 0, 4 * sizeof(float), stream);
  fused_kernel<<<dim3(2304), dim3(256), 0, stream>>>(conv_in, K, bias, out, logdet);
}

// Round 7
// 1666.546 us; speedup vs baseline: 1.0990x; 1.0990x over previous
//
#include <hip/hip_runtime.h>
#include <hip/hip_fp16.h>
#include <math.h>

#define TAU 0.5f   // |pivot|^2 threshold (f32) for the fast pivot path

// ---------------------------------------------------------------------------
// Fused kernel: 2304 blocks x 256 threads (9 blocks/CU exactly).
//   bid < 256   -> conv block,  cid = bid       (conv-first: r19's -10us win)
//   bid >= 256  -> logdet block, lid = bid-256 (0..2047); lid<2 blocks run
//                  TWO keys (lid, lid+2048) via a FORCED-ROLLED rep loop.
//                  They start first -> extra work hides in steady state,
//                  removing the 2-CU 10th-block tail of the 2306 grid.
//
// r22 post-mortem of r21: LDS pivot-row broadcast spilled catastrophically
//   (WRITE_SIZE 4.3MB->3.0GB, FETCH->1.5GB, VALUBusy 62->7.6%, dur 294->1798us).
//   ds_*_b128 quads force aligned consecutive-VGPR staging copies of a2
//   slices -> pressure cliff; and/or rep-loop body duplication. VERDICT:
//   any a2 marshalling into aligned quads is banned; readlane loop reads a2
//   in place and stays. #pragma unroll 1 on the rep loop prevents peeling.
// Logdet inner loop = r12 verbatim (readlane broadcast, op_sel-folded swap):
// r8/r13/r14: DS broadcasts + SALU swaps regress. r16-r18: LDS column
// staging spills or is neutral. r21: LDS pivot broadcast spills.
// ---------------------------------------------------------------------------
__device__ __forceinline__ int h2i(__half2 h) { int i; __builtin_memcpy(&i, &h, 4); return i; }
__device__ __forceinline__ __half2 i2h(int i) { __half2 h; __builtin_memcpy(&h, &i, 4); return h; }

__global__ __launch_bounds__(256, 3) void fused_kernel(
    const float* __restrict__ x, const float* __restrict__ K,
    const float* __restrict__ bias, float* __restrict__ out,
    float* __restrict__ logdet) {
  __shared__ float smem[4928];               // conv: w[576] + tile[64*68]
  int bid = blockIdx.x;
  int t = threadIdx.x;

  if (bid < 256) {
    // ================= conv =================
    int b = bid >> 6, co = bid & 63;
    float* w = smem;                         // 576
    float* tile = smem + 576;                // 64*68 (stride 68: 16B-aligned)

    for (int i = t; i < 576; i += 256) {
      float vv = K[(size_t)((b * 64 + co) * 64) * 9 + i];
      if (i == co * 9 + 4) vv += 1.0f;       // identity: ci==co, center tap
      w[i] = vv;
    }

    int ty = t >> 2;
    int tx = t & 3;
    int x0 = tx << 4;
    float bval = bias[b * 64 + co];
    float acc[16];
#pragma unroll
    for (int i = 0; i < 16; ++i) acc[i] = bval;

    const float* xb = x + (size_t)(b * 64) * 4096;
    for (int ci = 0; ci < 64; ++ci) {
      __syncthreads();                       // WAR on tile (and w on first iter)
      const float4* xc4 = (const float4*)(xb + (size_t)ci * 4096);
#pragma unroll
      for (int j = 0; j < 4; ++j) {          // 4x (dwordx4 load + b128 LDS write)
        int i4 = t + 256 * j;                // float4 index 0..1023
        int row = i4 >> 4;                   // 16 float4 per 64-wide row
        int col = (i4 & 15) << 2;
        float4 vv = xc4[i4];
        *(float4*)&tile[row * 68 + col] = vv;
      }
      __syncthreads();

      float w0 = w[ci * 9 + 0], w1 = w[ci * 9 + 1], w2 = w[ci * 9 + 2];
      float w3 = w[ci * 9 + 3], w4 = w[ci * 9 + 4], w5 = w[ci * 9 + 5];
      float w6 = w[ci * 9 + 6], w7 = w[ci * 9 + 7], w8 = w[ci * 9 + 8];

      int ym = ((ty - 1) & 63) * 68;
      int yc = ty * 68;
      int yp = ((ty + 1) & 63) * 68;
      float in0[18], in1[18], in2[18];
#pragma unroll
      for (int q = 0; q < 4; ++q) {          // interior: 12x ds_read_b128
        float4 v0 = *(const float4*)&tile[ym + x0 + 4 * q];
        float4 v1 = *(const float4*)&tile[yc + x0 + 4 * q];
        float4 v2 = *(const float4*)&tile[yp + x0 + 4 * q];
        in0[1 + 4 * q] = v0.x; in0[2 + 4 * q] = v0.y; in0[3 + 4 * q] = v0.z; in0[4 + 4 * q] = v0.w;
        in1[1 + 4 * q] = v1.x; in1[2 + 4 * q] = v1.y; in1[3 + 4 * q] = v1.z; in1[4 + 4 * q] = v1.w;
        in2[1 + 4 * q] = v2.x; in2[2 + 4 * q] = v2.y; in2[3 + 4 * q] = v2.z; in2[4 + 4 * q] = v2.w;
      }
      in0[0]  = tile[ym + ((x0 - 1) & 63)];  // 6 scalar edge reads (wrap)
      in0[17] = tile[ym + ((x0 + 16) & 63)];
      in1[0]  = tile[yc + ((x0 - 1) & 63)];
      in1[17] = tile[yc + ((x0 + 16) & 63)];
      in2[0]  = tile[yp + ((x0 - 1) & 63)];
      in2[17] = tile[yp + ((x0 + 16) & 63)];
#pragma unroll
      for (int px = 0; px < 16; ++px) {
        float a = acc[px];
        a = fmaf(w0, in0[px], a); a = fmaf(w1, in0[px + 1], a); a = fmaf(w2, in0[px + 2], a);
        a = fmaf(w3, in1[px], a); a = fmaf(w4, in1[px + 1], a); a = fmaf(w5, in1[px + 2], a);
        a = fmaf(w6, in2[px], a); a = fmaf(w7, in2[px + 1], a); a = fmaf(w8, in2[px + 2], a);
        acc[px] = a;
      }
    }

    float* op = out + (size_t)(b * 64 + co) * 4096 + ty * 64 + x0;
#pragma unroll
    for (int i = 0; i < 16; i += 4) {
      *(float4*)(op + i) = make_float4(acc[i], acc[i + 1], acc[i + 2], acc[i + 3]);
    }
    return;
  }

  // ================= logdet =================
  int lid = bid - 256;                       // 0..2047
  int b = t >> 6;                            // wave id == batch
  int r = t & 63;                            // lane == matrix row

  int nrep = (lid < 2) ? 2 : 1;
#pragma unroll 1
  for (int rep = 0; rep < nrep; ++rep) {
    int key = lid + (rep << 11);             // second key = lid + 2048
    int u, v;
    if (key < 33) { u = 0; v = key; }
    else if (key < 2017) { int q = key - 33; u = 1 + (q >> 6); v = q & 63; }
    else { u = 32; v = key - 2017; }
    float weight = (((u & 31) == 0) && ((v & 31) == 0)) ? 1.0f : 2.0f;

    // twiddles w[kh*3+kw] = e^{-2*pi*i*(u*kh+v*kw)/64} via complex power products
    float Ar[3], Ai[3], Br[3], Bi[3];
    {
      const float k2pi = -6.283185307179586f / 64.0f;
      float su, cu, sv, cv;
      __sincosf(k2pi * (float)u, &su, &cu);
      __sincosf(k2pi * (float)v, &sv, &cv);
      Ar[0] = 1.0f; Ai[0] = 0.0f; Ar[1] = cu; Ai[1] = su;
      Ar[2] = cu * cu - su * su; Ai[2] = 2.0f * cu * su;
      Br[0] = 1.0f; Bi[0] = 0.0f; Br[1] = cv; Bi[1] = sv;
      Br[2] = cv * cv - sv * sv; Bi[2] = 2.0f * cv * sv;
    }
    float wr[9], wi[9];
#pragma unroll
    for (int kh = 0; kh < 3; ++kh)
#pragma unroll
      for (int kw = 0; kw < 3; ++kw) {
        wr[kh * 3 + kw] = Ar[kh] * Br[kw] - Ai[kh] * Bi[kw];
        wi[kh * 3 + kw] = Ar[kh] * Bi[kw] + Ai[kh] * Br[kw];
      }

    // Build row r of Khat in fp32, pack each column to f16x2 immediately.
    __half2 a2[65];
    const float4* Kp4 = (const float4*)(K + (size_t)(b * 64 + r) * 576);
#pragma unroll
    for (int g = 0; g < 16; ++g) {           // 16 groups x 4 columns
      float f[36];
#pragma unroll
      for (int qq = 0; qq < 9; ++qq) {
        float4 vv = Kp4[g * 9 + qq];
        f[qq * 4 + 0] = vv.x; f[qq * 4 + 1] = vv.y; f[qq * 4 + 2] = vv.z; f[qq * 4 + 3] = vv.w;
      }
#pragma unroll
      for (int cc = 0; cc < 4; ++cc) {
        int c = g * 4 + cc;
        float re = 0.0f, im = 0.0f;
#pragma unroll
        for (int t9 = 0; t9 < 9; ++t9) {
          float kv = f[cc * 9 + t9];
          re = fmaf(kv, wr[t9], re);
          im = fmaf(kv, wi[t9], im);
        }
        if (c == r) { re += wr[4]; im += wi[4]; }  // identity: center-tap delta
        a2[c] = __floats2half2_rn(re, im);
      }
    }
    a2[64] = __floats2half2_rn(0.0f, 0.0f);  // pad slot for chunk overshoot

    bool active = true;
    float pivmag = 1.0f;                     // each lane's own pivot |.|^2 (f32)

    for (int k = 0; k < 63; ++k) {
      float fr0 = __low2float(a2[0]);
      float fi0 = __high2float(a2[0]);
      float mag = fmaf(fr0, fr0, fi0 * fi0);
      bool cand = active && (mag >= TAU);
      unsigned long long candm = __ballot(cand);
      int p;
      if (candm != 0ULL) {
        p = __ffsll(candm) - 1;              // fast path: first big-enough pivot
      } else {                               // rare: all remaining pivots tiny
        float mm = active ? mag : -1.0f;
#pragma unroll
        for (int off = 32; off > 0; off >>= 1) mm = fmaxf(mm, __shfl_xor(mm, off));
        unsigned long long mx = __ballot(active && (mag == mm));
        if (mx == 0ULL) mx = __ballot(active); // degenerate (NaN) guard
        p = __ffsll(mx) - 1;
      }
      p &= 63;                               // uniform (ballot-derived), valid lane

      bool isPiv = (r == p);
      pivmag = isPiv ? mag : pivmag;         // latch; log deferred to the end
      active = active && !isPiv;

      __half2 pivh = i2h(__builtin_amdgcn_readlane(h2i(a2[0]), p));
      float pr = __low2float(pivh);
      float pi = __high2float(pivh);
      float inv = __builtin_amdgcn_rcpf(fmaf(pr, pr, pi * pi));
      float fre = (fr0 * pr + fi0 * pi) * inv;
      float fim = (fi0 * pr - fr0 * pi) * inv;
      fre = active ? fre : 0.0f;             // pivot + retired lanes: shift-only
      fim = active ? fim : 0.0f;
      __half2 nfre2 = __float2half2_rn(-fre);                   // (-fre, -fre)
      __half2 fim2 = __halves2half2(__float2half_rn(fim),
                                    __float2half_rn(-fim));     // (fim, -fim)

      int rem = 63 - k;                      // remaining columns at slots 1..rem
#pragma unroll
      for (int ch = 0; ch < 8; ++ch) {
        if (ch * 8 < rem) {                  // uniform scalar guard, chunk=8
          int c0 = ch * 8 + 1;
          int Li[8];
#pragma unroll
          for (int e = 0; e < 8; ++e)        // batch: 8 readlanes (packed rows)
            Li[e] = __builtin_amdgcn_readlane(h2i(a2[c0 + e]), p);
#pragma unroll
          for (int e = 0; e < 8; ++e) {
            __half2 P = i2h(Li[e]);
            // (re',im') = (re,im) - fre*(lr,li) + fim*(li,-lr): 2 pk_fma
            // (__lowhigh2highlow folds into pk_fma op_sel -- r13 errata)
            __half2 tmp = __hfma2(nfre2, P, a2[c0 + e]);
            a2[c0 + e - 1] = __hfma2(fim2, __lowhigh2highlow(P), tmp);
          }
        }
      }
    }
    {
      float fr0 = __low2float(a2[0]);
      float fi0 = __high2float(a2[0]);
      if (active) pivmag = fmaf(fr0, fr0, fi0 * fi0);  // last surviving row
    }

    float logsum = 0.5f * __logf(pivmag);    // one log per lane; sum = logdet
#pragma unroll
    for (int off = 32; off > 0; off >>= 1) logsum += __shfl_xor(logsum, off);
    if (r == 0) atomicAdd(&logdet[b], weight * logsum);
  }
}

// ---------------------------------------------------------------------------
extern "C" void kernel_launch(void* const* d_in, const int* in_sizes, int n_in,
                              void* d_out, int out_size, void* d_ws, size_t ws_size,
                              hipStream_t stream) {
  const float* conv_in = (const float*)d_in[0];   // [4,64,64,64]
  const float* K       = (const float*)d_in[1];   // [4,64,64,3,3]
  const float* bias    = (const float*)d_in[2];   // [4,64,1,1]
  float* out = (float*)d_out;                     // conv_out (1048576) ++ logdet (4)
  float* logdet = out + 1048576;

  hipMemsetAsync(logdet, 0, 4 * sizeof(float), stream);
  fused_kernel<<<dim3(2304), dim3(256), 0, stream>>>(conv_in, K, bias, out, logdet);
}

// Round 8
// 318.144 us; speedup vs baseline: 5.7571x; 5.2383x over previous
//
#include <hip/hip_runtime.h>
#include <hip/hip_fp16.h>
#include <math.h>

#define TAU 0.5f   // |pivot|^2 threshold (f32) for the fast pivot path

// ---------------------------------------------------------------------------
// Fused kernel: 2304 blocks x 256 threads (9 blocks/CU exactly).
//   bid < 256  -> conv block (conv-first: r19's -10us win).
//                 bid 0,1 FALL THROUGH into logdet with key 2048+bid.
//   bid >= 256 -> logdet block, key = bid-256 (0..2047).
//
// r23 post-mortem of r21/r22: the SPILL TRIGGER is a runtime-trip-count
//   loop wrapping the logdet body (r22 spilled with the r20-verbatim inner
//   loop inside "#pragma unroll 1 for(rep)": WRITE 2.77GB, dur 1634us).
//   a2[65] demotes to scratch when the body sits behind a loop back-edge.
//   RULE: logdet body must be straight-line single-entry code. The 2 extra
//   keys (2048,2049) are handled by conv blocks 0,1 falling through after
//   conv -- no loop, key is a phi. Sequential pressure, not additive.
// Logdet inner loop = r12/r20 verbatim (readlane broadcast, op_sel swap):
// r8/r13/r14: DS broadcasts + SALU swaps regress. r16-r18: LDS column
// staging spills or is neutral. r21/r22: loop-wrapped body spills.
// ---------------------------------------------------------------------------
__device__ __forceinline__ int h2i(__half2 h) { int i; __builtin_memcpy(&i, &h, 4); return i; }
__device__ __forceinline__ __half2 i2h(int i) { __half2 h; __builtin_memcpy(&h, &i, 4); return h; }

__global__ __launch_bounds__(256, 3) void fused_kernel(
    const float* __restrict__ x, const float* __restrict__ K,
    const float* __restrict__ bias, float* __restrict__ out,
    float* __restrict__ logdet) {
  __shared__ float smem[4928];               // conv: w[576] + tile[64*68]
  int bid = blockIdx.x;
  int t = threadIdx.x;

  int key;                                   // logdet key (phi: two sources)
  if (bid < 256) {
    // ================= conv =================
    int b = bid >> 6, co = bid & 63;
    float* w = smem;                         // 576
    float* tile = smem + 576;                // 64*68 (stride 68: 16B-aligned)

    for (int i = t; i < 576; i += 256) {
      float vv = K[(size_t)((b * 64 + co) * 64) * 9 + i];
      if (i == co * 9 + 4) vv += 1.0f;       // identity: ci==co, center tap
      w[i] = vv;
    }

    int ty = t >> 2;
    int tx = t & 3;
    int x0 = tx << 4;
    float bval = bias[b * 64 + co];
    float acc[16];
#pragma unroll
    for (int i = 0; i < 16; ++i) acc[i] = bval;

    const float* xb = x + (size_t)(b * 64) * 4096;
    for (int ci = 0; ci < 64; ++ci) {
      __syncthreads();                       // WAR on tile (and w on first iter)
      const float4* xc4 = (const float4*)(xb + (size_t)ci * 4096);
#pragma unroll
      for (int j = 0; j < 4; ++j) {          // 4x (dwordx4 load + b128 LDS write)
        int i4 = t + 256 * j;                // float4 index 0..1023
        int row = i4 >> 4;                   // 16 float4 per 64-wide row
        int col = (i4 & 15) << 2;
        float4 vv = xc4[i4];
        *(float4*)&tile[row * 68 + col] = vv;
      }
      __syncthreads();

      float w0 = w[ci * 9 + 0], w1 = w[ci * 9 + 1], w2 = w[ci * 9 + 2];
      float w3 = w[ci * 9 + 3], w4 = w[ci * 9 + 4], w5 = w[ci * 9 + 5];
      float w6 = w[ci * 9 + 6], w7 = w[ci * 9 + 7], w8 = w[ci * 9 + 8];

      int ym = ((ty - 1) & 63) * 68;
      int yc = ty * 68;
      int yp = ((ty + 1) & 63) * 68;
      float in0[18], in1[18], in2[18];
#pragma unroll
      for (int q = 0; q < 4; ++q) {          // interior: 12x ds_read_b128
        float4 v0 = *(const float4*)&tile[ym + x0 + 4 * q];
        float4 v1 = *(const float4*)&tile[yc + x0 + 4 * q];
        float4 v2 = *(const float4*)&tile[yp + x0 + 4 * q];
        in0[1 + 4 * q] = v0.x; in0[2 + 4 * q] = v0.y; in0[3 + 4 * q] = v0.z; in0[4 + 4 * q] = v0.w;
        in1[1 + 4 * q] = v1.x; in1[2 + 4 * q] = v1.y; in1[3 + 4 * q] = v1.z; in1[4 + 4 * q] = v1.w;
        in2[1 + 4 * q] = v2.x; in2[2 + 4 * q] = v2.y; in2[3 + 4 * q] = v2.z; in2[4 + 4 * q] = v2.w;
      }
      in0[0]  = tile[ym + ((x0 - 1) & 63)];  // 6 scalar edge reads (wrap)
      in0[17] = tile[ym + ((x0 + 16) & 63)];
      in1[0]  = tile[yc + ((x0 - 1) & 63)];
      in1[17] = tile[yc + ((x0 + 16) & 63)];
      in2[0]  = tile[yp + ((x0 - 1) & 63)];
      in2[17] = tile[yp + ((x0 + 16) & 63)];
#pragma unroll
      for (int px = 0; px < 16; ++px) {
        float a = acc[px];
        a = fmaf(w0, in0[px], a); a = fmaf(w1, in0[px + 1], a); a = fmaf(w2, in0[px + 2], a);
        a = fmaf(w3, in1[px], a); a = fmaf(w4, in1[px + 1], a); a = fmaf(w5, in1[px + 2], a);
        a = fmaf(w6, in2[px], a); a = fmaf(w7, in2[px + 1], a); a = fmaf(w8, in2[px + 2], a);
        acc[px] = a;
      }
    }

    float* op = out + (size_t)(b * 64 + co) * 4096 + ty * 64 + x0;
#pragma unroll
    for (int i = 0; i < 16; i += 4) {
      *(float4*)(op + i) = make_float4(acc[i], acc[i + 1], acc[i + 2], acc[i + 3]);
    }

    if (bid >= 2) return;                    // blocks 0,1 continue to logdet
    key = 2048 + bid;                        // keys 2048, 2049
  } else {
    key = bid - 256;                         // 0..2047
  }

  // ================= logdet (straight-line, single entry) =================
  int b = t >> 6;                            // wave id == batch
  int r = t & 63;                            // lane == matrix row

  int u, v;
  if (key < 33) { u = 0; v = key; }
  else if (key < 2017) { int q = key - 33; u = 1 + (q >> 6); v = q & 63; }
  else { u = 32; v = key - 2017; }
  float weight = (((u & 31) == 0) && ((v & 31) == 0)) ? 1.0f : 2.0f;

  // twiddles w[kh*3+kw] = e^{-2*pi*i*(u*kh+v*kw)/64} via complex power products
  float Ar[3], Ai[3], Br[3], Bi[3];
  {
    const float k2pi = -6.283185307179586f / 64.0f;
    float su, cu, sv, cv;
    __sincosf(k2pi * (float)u, &su, &cu);
    __sincosf(k2pi * (float)v, &sv, &cv);
    Ar[0] = 1.0f; Ai[0] = 0.0f; Ar[1] = cu; Ai[1] = su;
    Ar[2] = cu * cu - su * su; Ai[2] = 2.0f * cu * su;
    Br[0] = 1.0f; Bi[0] = 0.0f; Br[1] = cv; Bi[1] = sv;
    Br[2] = cv * cv - sv * sv; Bi[2] = 2.0f * cv * sv;
  }
  float wr[9], wi[9];
#pragma unroll
  for (int kh = 0; kh < 3; ++kh)
#pragma unroll
    for (int kw = 0; kw < 3; ++kw) {
      wr[kh * 3 + kw] = Ar[kh] * Br[kw] - Ai[kh] * Bi[kw];
      wi[kh * 3 + kw] = Ar[kh] * Bi[kw] + Ai[kh] * Br[kw];
    }

  // Build row r of Khat in fp32, pack each column to f16x2 immediately.
  __half2 a2[65];
  const float4* Kp4 = (const float4*)(K + (size_t)(b * 64 + r) * 576);
#pragma unroll
  for (int g = 0; g < 16; ++g) {             // 16 groups x 4 columns
    float f[36];
#pragma unroll
    for (int qq = 0; qq < 9; ++qq) {
      float4 vv = Kp4[g * 9 + qq];
      f[qq * 4 + 0] = vv.x; f[qq * 4 + 1] = vv.y; f[qq * 4 + 2] = vv.z; f[qq * 4 + 3] = vv.w;
    }
#pragma unroll
    for (int cc = 0; cc < 4; ++cc) {
      int c = g * 4 + cc;
      float re = 0.0f, im = 0.0f;
#pragma unroll
      for (int t9 = 0; t9 < 9; ++t9) {
        float kv = f[cc * 9 + t9];
        re = fmaf(kv, wr[t9], re);
        im = fmaf(kv, wi[t9], im);
      }
      if (c == r) { re += wr[4]; im += wi[4]; }  // identity: center-tap delta
      a2[c] = __floats2half2_rn(re, im);
    }
  }
  a2[64] = __floats2half2_rn(0.0f, 0.0f);    // pad slot for chunk overshoot

  bool active = true;
  float pivmag = 1.0f;                       // each lane's own pivot |.|^2 (f32)

  for (int k = 0; k < 63; ++k) {
    float fr0 = __low2float(a2[0]);
    float fi0 = __high2float(a2[0]);
    float mag = fmaf(fr0, fr0, fi0 * fi0);
    bool cand = active && (mag >= TAU);
    unsigned long long candm = __ballot(cand);
    int p;
    if (candm != 0ULL) {
      p = __ffsll(candm) - 1;                // fast path: first big-enough pivot
    } else {                                 // rare: all remaining pivots tiny
      float mm = active ? mag : -1.0f;
#pragma unroll
      for (int off = 32; off > 0; off >>= 1) mm = fmaxf(mm, __shfl_xor(mm, off));
      unsigned long long mx = __ballot(active && (mag == mm));
      if (mx == 0ULL) mx = __ballot(active); // degenerate (NaN) guard
      p = __ffsll(mx) - 1;
    }
    p &= 63;                                 // uniform (ballot-derived), valid lane

    bool isPiv = (r == p);
    pivmag = isPiv ? mag : pivmag;           // latch; log deferred to the end
    active = active && !isPiv;

    __half2 pivh = i2h(__builtin_amdgcn_readlane(h2i(a2[0]), p));
    float pr = __low2float(pivh);
    float pi = __high2float(pivh);
    float inv = __builtin_amdgcn_rcpf(fmaf(pr, pr, pi * pi));
    float fre = (fr0 * pr + fi0 * pi) * inv;
    float fim = (fi0 * pr - fr0 * pi) * inv;
    fre = active ? fre : 0.0f;               // pivot + retired lanes: shift-only
    fim = active ? fim : 0.0f;
    __half2 nfre2 = __float2half2_rn(-fre);                     // (-fre, -fre)
    __half2 fim2 = __halves2half2(__float2half_rn(fim),
                                  __float2half_rn(-fim));       // (fim, -fim)

    int rem = 63 - k;                        // remaining columns at slots 1..rem
#pragma unroll
    for (int ch = 0; ch < 8; ++ch) {
      if (ch * 8 < rem) {                    // uniform scalar guard, chunk=8
        int c0 = ch * 8 + 1;
        int Li[8];
#pragma unroll
        for (int e = 0; e < 8; ++e)          // batch: 8 readlanes (packed rows)
          Li[e] = __builtin_amdgcn_readlane(h2i(a2[c0 + e]), p);
#pragma unroll
        for (int e = 0; e < 8; ++e) {
          __half2 P = i2h(Li[e]);
          // (re',im') = (re,im) - fre*(lr,li) + fim*(li,-lr): 2 pk_fma
          // (__lowhigh2highlow folds into pk_fma op_sel -- r13 errata)
          __half2 tmp = __hfma2(nfre2, P, a2[c0 + e]);
          a2[c0 + e - 1] = __hfma2(fim2, __lowhigh2highlow(P), tmp);
        }
      }
    }
  }
  {
    float fr0 = __low2float(a2[0]);
    float fi0 = __high2float(a2[0]);
    if (active) pivmag = fmaf(fr0, fr0, fi0 * fi0);  // last surviving row
  }

  float logsum = 0.5f * __logf(pivmag);      // one log per lane; sum = logdet
#pragma unroll
  for (int off = 32; off > 0; off >>= 1) logsum += __shfl_xor(logsum, off);
  if (r == 0) atomicAdd(&logdet[b], weight * logsum);
}

// ---------------------------------------------------------------------------
extern "C" void kernel_launch(void* const* d_in, const int* in_sizes, int n_in,
                              void* d_out, int out_size, void* d_ws, size_t ws_size,
                              hipStream_t stream) {
  const float* conv_in = (const float*)d_in[0];   // [4,64,64,64]
  const float* K       = (const float*)d_in[1];   // [4,64,64,3,3]
  const float* bias    = (const float*)d_in[2];   // [4,64,1,1]
  float* out = (float*)d_out;                     // conv_out (1048576) ++ logdet (4)
  float* logdet = out + 1048576;

  hipMemsetAsync(logdet, 0, 4 * sizeof(float), stream);
  fused_kernel<<<dim3(2304), dim3(256), 0, stream>>>(conv_in, K, bias, out, logdet);
}

// Round 9
// 306.251 us; speedup vs baseline: 5.9807x; 1.0388x over previous
//
#include <hip/hip_runtime.h>
#include <hip/hip_fp16.h>
#include <math.h>

#define TAU 0.5f   // |pivot|^2 threshold (f32) for the fast pivot path

// ---------------------------------------------------------------------------
// Fused kernel: 2304 blocks x 256 threads (9 blocks/CU exactly).
//   bid < 256  -> conv block (conv-first). bid 0,1 FALL THROUGH into logdet
//                 with key 2048+bid (straight-line; loop-wrapping spills).
//   bid >= 256 -> logdet block, key = bid-256 (0..2047).
//
// r24 delta: k-loop instruction diet. Invariant r12..r23: VALUBusy*dur ~=
//   180us at ~60% across 8-32 waves/CU -> the cap is the STREAM MIX, not
//   TLP. Removed non-VALU pollution:
//   1. STAGED k-loop: chunk count ceil(rem/8) is a static staircase ->
//      8 loops with constant chunk counts (7+8x7 = 63 steps). Kills all
//      504 per-k guard cmp+branches. Bodies = r12 pattern verbatim,
//      static a2 indices, #pragma unroll 1 per stage.
//   2. fre/fim cndmasks removed: retired/pivot rows self-eliminate;
//      their values are never read (readlane targets future pivots only)
//      -> live-path outputs bit-identical.
//   3. magp via readlane(mag,p) (was recomputed pr^2+pi^2): shorter
//      serial prefix chain.
// Ledger: r8/r13/r14 DS broadcasts + SALU swaps regress; r16-r18 LDS
// column staging spills/neutral; r21 b128 marshalling spills; r22 runtime
// rep-loop around body spills. Straight-line body + static indices only.
// ---------------------------------------------------------------------------
__device__ __forceinline__ int h2i(__half2 h) { int i; __builtin_memcpy(&i, &h, 4); return i; }
__device__ __forceinline__ __half2 i2h(int i) { __half2 h; __builtin_memcpy(&h, &i, 4); return h; }

#define UPD(SL, LV) {                                                     \
    __half2 P_ = i2h(LV);                                                 \
    __half2 t_ = __hfma2(nfre2, P_, a2[SL]);                              \
    a2[(SL) - 1] = __hfma2(fim2, __lowhigh2highlow(P_), t_); }

#define CHUNK(CH) {                                                       \
    int l0 = __builtin_amdgcn_readlane(h2i(a2[(CH) * 8 + 1]), p);         \
    int l1 = __builtin_amdgcn_readlane(h2i(a2[(CH) * 8 + 2]), p);         \
    int l2 = __builtin_amdgcn_readlane(h2i(a2[(CH) * 8 + 3]), p);         \
    int l3 = __builtin_amdgcn_readlane(h2i(a2[(CH) * 8 + 4]), p);         \
    int l4 = __builtin_amdgcn_readlane(h2i(a2[(CH) * 8 + 5]), p);         \
    int l5 = __builtin_amdgcn_readlane(h2i(a2[(CH) * 8 + 6]), p);         \
    int l6 = __builtin_amdgcn_readlane(h2i(a2[(CH) * 8 + 7]), p);         \
    int l7 = __builtin_amdgcn_readlane(h2i(a2[(CH) * 8 + 8]), p);         \
    UPD((CH) * 8 + 1, l0) UPD((CH) * 8 + 2, l1) UPD((CH) * 8 + 3, l2)     \
    UPD((CH) * 8 + 4, l3) UPD((CH) * 8 + 5, l4) UPD((CH) * 8 + 6, l5)     \
    UPD((CH) * 8 + 7, l6) UPD((CH) * 8 + 8, l7) }

#define PREFIX()                                                          \
    float fr0 = __low2float(a2[0]);                                       \
    float fi0 = __high2float(a2[0]);                                      \
    float mag = fmaf(fr0, fr0, fi0 * fi0);                                \
    unsigned long long candm = __ballot(active && (mag >= TAU));          \
    int p;                                                                \
    if (candm != 0ULL) {                                                  \
      p = __ffsll(candm) - 1;                                             \
    } else {                                                              \
      float mm = active ? mag : -1.0f;                                    \
      for (int off = 32; off > 0; off >>= 1)                              \
        mm = fmaxf(mm, __shfl_xor(mm, off));                              \
      unsigned long long mx = __ballot(active && (mag == mm));            \
      if (mx == 0ULL) mx = __ballot(active);                              \
      p = __ffsll(mx) - 1;                                                \
    }                                                                     \
    p &= 63;                                                              \
    bool isPiv = (r == p);                                                \
    pivmag = isPiv ? mag : pivmag;                                        \
    active = active && !isPiv;                                            \
    float magp = __int_as_float(                                          \
        __builtin_amdgcn_readlane(__float_as_int(mag), p));               \
    __half2 pivh = i2h(__builtin_amdgcn_readlane(h2i(a2[0]), p));         \
    float pr = __low2float(pivh);                                         \
    float pi = __high2float(pivh);                                        \
    float inv = __builtin_amdgcn_rcpf(magp);                              \
    float fre = (fr0 * pr + fi0 * pi) * inv;                              \
    float fim = (fi0 * pr - fr0 * pi) * inv;                              \
    __half2 nfre2 = __float2half2_rn(-fre);                               \
    __half2 fim2 = __halves2half2(__float2half_rn(fim),                   \
                                  __float2half_rn(-fim));

__global__ __launch_bounds__(256, 3) void fused_kernel(
    const float* __restrict__ x, const float* __restrict__ K,
    const float* __restrict__ bias, float* __restrict__ out,
    float* __restrict__ logdet) {
  __shared__ float smem[4928];               // conv: w[576] + tile[64*68]
  int bid = blockIdx.x;
  int t = threadIdx.x;

  int key;                                   // logdet key (phi: two sources)
  if (bid < 256) {
    // ================= conv =================
    int b = bid >> 6, co = bid & 63;
    float* w = smem;                         // 576
    float* tile = smem + 576;                // 64*68 (stride 68: 16B-aligned)

    for (int i = t; i < 576; i += 256) {
      float vv = K[(size_t)((b * 64 + co) * 64) * 9 + i];
      if (i == co * 9 + 4) vv += 1.0f;       // identity: ci==co, center tap
      w[i] = vv;
    }

    int ty = t >> 2;
    int tx = t & 3;
    int x0 = tx << 4;
    float bval = bias[b * 64 + co];
    float acc[16];
#pragma unroll
    for (int i = 0; i < 16; ++i) acc[i] = bval;

    const float* xb = x + (size_t)(b * 64) * 4096;
    for (int ci = 0; ci < 64; ++ci) {
      __syncthreads();                       // WAR on tile (and w on first iter)
      const float4* xc4 = (const float4*)(xb + (size_t)ci * 4096);
#pragma unroll
      for (int j = 0; j < 4; ++j) {          // 4x (dwordx4 load + b128 LDS write)
        int i4 = t + 256 * j;                // float4 index 0..1023
        int row = i4 >> 4;                   // 16 float4 per 64-wide row
        int col = (i4 & 15) << 2;
        float4 vv = xc4[i4];
        *(float4*)&tile[row * 68 + col] = vv;
      }
      __syncthreads();

      float w0 = w[ci * 9 + 0], w1 = w[ci * 9 + 1], w2 = w[ci * 9 + 2];
      float w3 = w[ci * 9 + 3], w4 = w[ci * 9 + 4], w5 = w[ci * 9 + 5];
      float w6 = w[ci * 9 + 6], w7 = w[ci * 9 + 7], w8 = w[ci * 9 + 8];

      int ym = ((ty - 1) & 63) * 68;
      int yc = ty * 68;
      int yp = ((ty + 1) & 63) * 68;
      float in0[18], in1[18], in2[18];
#pragma unroll
      for (int q = 0; q < 4; ++q) {          // interior: 12x ds_read_b128
        float4 v0 = *(const float4*)&tile[ym + x0 + 4 * q];
        float4 v1 = *(const float4*)&tile[yc + x0 + 4 * q];
        float4 v2 = *(const float4*)&tile[yp + x0 + 4 * q];
        in0[1 + 4 * q] = v0.x; in0[2 + 4 * q] = v0.y; in0[3 + 4 * q] = v0.z; in0[4 + 4 * q] = v0.w;
        in1[1 + 4 * q] = v1.x; in1[2 + 4 * q] = v1.y; in1[3 + 4 * q] = v1.z; in1[4 + 4 * q] = v1.w;
        in2[1 + 4 * q] = v2.x; in2[2 + 4 * q] = v2.y; in2[3 + 4 * q] = v2.z; in2[4 + 4 * q] = v2.w;
      }
      in0[0]  = tile[ym + ((x0 - 1) & 63)];  // 6 scalar edge reads (wrap)
      in0[17] = tile[ym + ((x0 + 16) & 63)];
      in1[0]  = tile[yc + ((x0 - 1) & 63)];
      in1[17] = tile[yc + ((x0 + 16) & 63)];
      in2[0]  = tile[yp + ((x0 - 1) & 63)];
      in2[17] = tile[yp + ((x0 + 16) & 63)];
#pragma unroll
      for (int px = 0; px < 16; ++px) {
        float a = acc[px];
        a = fmaf(w0, in0[px], a); a = fmaf(w1, in0[px + 1], a); a = fmaf(w2, in0[px + 2], a);
        a = fmaf(w3, in1[px], a); a = fmaf(w4, in1[px + 1], a); a = fmaf(w5, in1[px + 2], a);
        a = fmaf(w6, in2[px], a); a = fmaf(w7, in2[px + 1], a); a = fmaf(w8, in2[px + 2], a);
        acc[px] = a;
      }
    }

    float* op = out + (size_t)(b * 64 + co) * 4096 + ty * 64 + x0;
#pragma unroll
    for (int i = 0; i < 16; i += 4) {
      *(float4*)(op + i) = make_float4(acc[i], acc[i + 1], acc[i + 2], acc[i + 3]);
    }

    if (bid >= 2) return;                    // blocks 0,1 continue to logdet
    key = 2048 + bid;                        // keys 2048, 2049
  } else {
    key = bid - 256;                         // 0..2047
  }

  // ================= logdet (straight-line, single entry) =================
  int b = t >> 6;                            // wave id == batch
  int r = t & 63;                            // lane == matrix row

  int u, v;
  if (key < 33) { u = 0; v = key; }
  else if (key < 2017) { int q = key - 33; u = 1 + (q >> 6); v = q & 63; }
  else { u = 32; v = key - 2017; }
  float weight = (((u & 31) == 0) && ((v & 31) == 0)) ? 1.0f : 2.0f;

  // twiddles w[kh*3+kw] = e^{-2*pi*i*(u*kh+v*kw)/64} via complex power products
  float Ar[3], Ai[3], Br[3], Bi[3];
  {
    const float k2pi = -6.283185307179586f / 64.0f;
    float su, cu, sv, cv;
    __sincosf(k2pi * (float)u, &su, &cu);
    __sincosf(k2pi * (float)v, &sv, &cv);
    Ar[0] = 1.0f; Ai[0] = 0.0f; Ar[1] = cu; Ai[1] = su;
    Ar[2] = cu * cu - su * su; Ai[2] = 2.0f * cu * su;
    Br[0] = 1.0f; Bi[0] = 0.0f; Br[1] = cv; Bi[1] = sv;
    Br[2] = cv * cv - sv * sv; Bi[2] = 2.0f * cv * sv;
  }
  float wr[9], wi[9];
#pragma unroll
  for (int kh = 0; kh < 3; ++kh)
#pragma unroll
    for (int kw = 0; kw < 3; ++kw) {
      wr[kh * 3 + kw] = Ar[kh] * Br[kw] - Ai[kh] * Bi[kw];
      wi[kh * 3 + kw] = Ar[kh] * Bi[kw] + Ai[kh] * Br[kw];
    }

  // Build row r of Khat in fp32, pack each column to f16x2 immediately.
  __half2 a2[65];
  const float4* Kp4 = (const float4*)(K + (size_t)(b * 64 + r) * 576);
#pragma unroll
  for (int g = 0; g < 16; ++g) {             // 16 groups x 4 columns
    float f[36];
#pragma unroll
    for (int qq = 0; qq < 9; ++qq) {
      float4 vv = Kp4[g * 9 + qq];
      f[qq * 4 + 0] = vv.x; f[qq * 4 + 1] = vv.y; f[qq * 4 + 2] = vv.z; f[qq * 4 + 3] = vv.w;
    }
#pragma unroll
    for (int cc = 0; cc < 4; ++cc) {
      int c = g * 4 + cc;
      float re = 0.0f, im = 0.0f;
#pragma unroll
      for (int t9 = 0; t9 < 9; ++t9) {
        float kv = f[cc * 9 + t9];
        re = fmaf(kv, wr[t9], re);
        im = fmaf(kv, wi[t9], im);
      }
      if (c == r) { re += wr[4]; im += wi[4]; }  // identity: center-tap delta
      a2[c] = __floats2half2_rn(re, im);
    }
  }
  a2[64] = __floats2half2_rn(0.0f, 0.0f);    // pad slot for chunk overshoot

  bool active = true;
  float pivmag = 1.0f;                       // each lane's own pivot |.|^2 (f32)

  // Staged elimination: 63 steps, chunk count = ceil(rem/8) staircase.
#pragma unroll 1
  for (int k = 0; k < 7; ++k) {              // rem 63..57
    PREFIX()
    CHUNK(0) CHUNK(1) CHUNK(2) CHUNK(3) CHUNK(4) CHUNK(5) CHUNK(6) CHUNK(7)
  }
#pragma unroll 1
  for (int k = 0; k < 8; ++k) {              // rem 56..49
    PREFIX()
    CHUNK(0) CHUNK(1) CHUNK(2) CHUNK(3) CHUNK(4) CHUNK(5) CHUNK(6)
  }
#pragma unroll 1
  for (int k = 0; k < 8; ++k) {              // rem 48..41
    PREFIX()
    CHUNK(0) CHUNK(1) CHUNK(2) CHUNK(3) CHUNK(4) CHUNK(5)
  }
#pragma unroll 1
  for (int k = 0; k < 8; ++k) {              // rem 40..33
    PREFIX()
    CHUNK(0) CHUNK(1) CHUNK(2) CHUNK(3) CHUNK(4)
  }
#pragma unroll 1
  for (int k = 0; k < 8; ++k) {              // rem 32..25
    PREFIX()
    CHUNK(0) CHUNK(1) CHUNK(2) CHUNK(3)
  }
#pragma unroll 1
  for (int k = 0; k < 8; ++k) {              // rem 24..17
    PREFIX()
    CHUNK(0) CHUNK(1) CHUNK(2)
  }
#pragma unroll 1
  for (int k = 0; k < 8; ++k) {              // rem 16..9
    PREFIX()
    CHUNK(0) CHUNK(1)
  }
#pragma unroll 1
  for (int k = 0; k < 8; ++k) {              // rem 8..1
    PREFIX()
    CHUNK(0)
  }

  {
    float fr0 = __low2float(a2[0]);
    float fi0 = __high2float(a2[0]);
    if (active) pivmag = fmaf(fr0, fr0, fi0 * fi0);  // last surviving row
  }

  float logsum = 0.5f * __logf(pivmag);      // one log per lane; sum = logdet
#pragma unroll
  for (int off = 32; off > 0; off >>= 1) logsum += __shfl_xor(logsum, off);
  if (r == 0) atomicAdd(&logdet[b], weight * logsum);
}

// ---------------------------------------------------------------------------
extern "C" void kernel_launch(void* const* d_in, const int* in_sizes, int n_in,
                              void* d_out, int out_size, void* d_ws, size_t ws_size,
                              hipStream_t stream) {
  const float* conv_in = (const float*)d_in[0];   // [4,64,64,64]
  const float* K       = (const float*)d_in[1];   // [4,64,64,3,3]
  const float* bias    = (const float*)d_in[2];   // [4,64,1,1]
  float* out = (float*)d_out;                     // conv_out (1048576) ++ logdet (4)
  float* logdet = out + 1048576;

  hipMemsetAsync(logdet, 0, 4 * sizeof(float), stream);
  fused_kernel<<<dim3(2304), dim3(256), 0, stream>>>(conv_in, K, bias, out, logdet);
}